// Round 6
// baseline (93.016 us; speedup 1.0000x reference)
//
#include <hip/hip_runtime.h>
#include <cstddef>

#define B_ 2
#define C_ 32
#define CP 33
#define W_ 256
#define H_ 256
#define X_ 512
#define Y_ 512
#define YT 32

typedef __bf16 bf16x8 __attribute__((ext_vector_type(8)));
typedef __bf16 bf16x4 __attribute__((ext_vector_type(4)));
typedef float  f32x4  __attribute__((ext_vector_type(4)));

#define AS1 __attribute__((address_space(1)))
#define AS3 __attribute__((address_space(3)))

__device__ __forceinline__ void gload16_lds(const void* g, void* l) {
    // async global->LDS, 16B per lane, dest = wave-uniform base + lane*16
    __builtin_amdgcn_global_load_lds((const AS1 void*)g, (AS3 void*)l, 16, 0, 0);
}

// ---------------- prep: bf16 tables ----------------
__global__ __launch_bounds__(256) void prep_kernel(
    const float* __restrict__ xin_lon, const float* __restrict__ xin_lat,
    const float* __restrict__ xout_lon, const float* __restrict__ xout_lat,
    const float* __restrict__ init_ls, const float* __restrict__ wt,
    __bf16* __restrict__ wlonT, __bf16* __restrict__ wlatT,
    __bf16* __restrict__ wt33)
{
    const int NLON = B_ * X_ * W_;
    const int NLAT = B_ * Y_ * H_;
    int t = blockIdx.x * 256 + threadIdx.x;
    float ls = init_ls[0];
    float cc = -0.5f / (ls * ls);
    if (t < NLON) {
        int b = t / (X_ * W_);
        int r = t - b * (X_ * W_);
        int x = r >> 8;
        int w = r & (W_ - 1);
        float d = xin_lon[b * W_ + w] - xout_lon[b * X_ + x];
        wlonT[t] = (__bf16)__expf(cc * d * d);
    } else if (t < NLON + NLAT) {
        int j = t - NLON;
        int b = j / (Y_ * H_);
        int r = j - b * (Y_ * H_);
        int y = r >> 8;
        int h = r & (H_ - 1);
        float d = xin_lat[b * H_ + h] - xout_lat[b * Y_ + y];
        wlatT[j] = (__bf16)__expf(cc * d * d);
    } else {
        int j = t - (NLON + NLAT);
        int o = j * 4;
        int b = o / (CP * W_ * H_);
        int r = o - b * (CP * W_ * H_);
        int co = r / (W_ * H_);
        int p = r & (W_ * H_ - 1);
        float4 v;
        bf16x4 ov;
        if (co == 0) {
            v = *(const float4*)&wt[((size_t)b * C_) * (W_ * H_) + p];
            ov[0] = (__bf16)((v.x != v.x) ? 0.f : 1.f);
            ov[1] = (__bf16)((v.y != v.y) ? 0.f : 1.f);
            ov[2] = (__bf16)((v.z != v.z) ? 0.f : 1.f);
            ov[3] = (__bf16)((v.w != v.w) ? 0.f : 1.f);
        } else {
            v = *(const float4*)&wt[((size_t)b * C_ + (co - 1)) * (W_ * H_) + p];
            ov[0] = (__bf16)((v.x != v.x) ? 0.f : v.x);
            ov[1] = (__bf16)((v.y != v.y) ? 0.f : v.y);
            ov[2] = (__bf16)((v.z != v.z) ? 0.f : v.z);
            ov[3] = (__bf16)((v.w != v.w) ? 0.f : v.w);
        }
        *(bf16x4*)&wt33[o] = ov;
    }
}

// ---------------- fused two-stage MFMA contraction ----------------
// stage1: U[w=256][y=32]   = sum_h wt33[ch][w][h] * wlatT[y][h]
// stage2: ee[x-chunk][y=32]= sum_w wlonT[x][w]   * U[w][y]
// A-operands staged per-wave via async global_load_lds, double-buffered,
// counted vmcnt (never 0 in steady state) — the compiler cannot undo this
// pipeline (round-5 lesson: register prefetch gets re-sunk, VGPR=52).
template<int NXQ, bool DENS>
__global__ __launch_bounds__(256, 2) void conv_mfma(
    const __bf16* __restrict__ wt33, const __bf16* __restrict__ wlonT,
    const __bf16* __restrict__ wlatT, float* __restrict__ eeT0,
    float* __restrict__ out)
{
    constexpr int XCH = X_ / NXQ;    // x per block
    constexpr int MT  = XCH / 64;    // stage-2 m-fragments per wave (4 or 2)

    __shared__ __bf16 Blat[8192];        // 16 KB
    __shared__ __bf16 Ut[8192];          // 16 KB
    __shared__ __bf16 Astage[16384];     // 32 KB: [wave][buf][frag(4)][lane*8]

    int b, ch, yt, xq;
    if (DENS) {
        b  = blockIdx.x / (16 * NXQ);
        int r = blockIdx.x - b * (16 * NXQ);
        yt = r / NXQ;
        xq = r - yt * NXQ;
        ch = 0;
    } else {
        int xcd = blockIdx.x & 7;
        int k   = blockIdx.x >> 3;   // 0..255
        int g   = k >> 5;            // 0..7
        int r   = k & 31;
        yt = r >> 1;
        xq = r & 1;
        int bc  = xcd * 8 + g;
        b  = bc >> 5;
        ch = (bc & 31) + 1;
    }
    const int y0   = yt * YT;
    const int t    = threadIdx.x;
    const int lane = t & 63;
    const int wave = t >> 6;
    const int lrow = lane & 15;
    const int lkg  = lane >> 4;

    // ---- stage wlatT y-tile into LDS (fragment-linear) ----
    {
        const __bf16* src = wlatT + ((size_t)b * Y_ + y0) * H_;
        int i = t;
#pragma unroll
        for (int it = 0; it < 4; ++it, i += 256) {
            int y = i >> 5, hc = i & 31;
            bf16x8 v = *(const bf16x8*)(src + y * H_ + hc * 8);
            int kt = hc >> 2, kg = hc & 3, nt = y >> 4;
            *(bf16x8*)&Blat[(((kt * 2 + nt) * 64) + kg * 16 + (y & 15)) * 8] = v;
        }
    }
    __syncthreads();

    const __bf16* wtc  = wt33 + ((size_t)b * CP + ch) * (W_ * H_);
    const __bf16* lonb = wlonT + (size_t)b * X_ * W_;

    // per-wave staging: issue FR async 16B-per-lane loads for one kt tile
    // rows stride 256 for both stages; identity lane mapping (lane reads back
    // its own 16B chunk).
    auto issue1 = [&](int kt, int buf) {
#pragma unroll
        for (int mt = 0; mt < 4; ++mt) {
            const __bf16* src = wtc + (size_t)(wave * 64 + mt * 16 + lrow) * H_
                                + kt * 32 + lkg * 8;
            gload16_lds((const void*)src,
                        (void*)&Astage[((wave * 2 + buf) * 4 + mt) * 512]);
        }
    };
    auto issue2 = [&](int kt, int buf) {
#pragma unroll
        for (int mt = 0; mt < MT; ++mt) {
            const __bf16* src = lonb + (size_t)(xq * XCH + wave * (XCH / 4)
                                + mt * 16 + lrow) * W_ + kt * 32 + lkg * 8;
            gload16_lds((const void*)src,
                        (void*)&Astage[((wave * 2 + buf) * 4 + mt) * 512]);
        }
    };

    // ---- stage 1 ----
    f32x4 acc1[4][2] = {};
    issue1(0, 0);
    issue1(1, 1);
#pragma unroll
    for (int kt = 0; kt < 8; ++kt) {
        if (kt == 7) asm volatile("s_waitcnt vmcnt(0)" ::: "memory");
        else         asm volatile("s_waitcnt vmcnt(4)" ::: "memory");
        const int buf = kt & 1;
        bf16x8 a[4];
#pragma unroll
        for (int mt = 0; mt < 4; ++mt)
            a[mt] = *(const bf16x8*)&Astage[((wave * 2 + buf) * 4 + mt) * 512 + lane * 8];
        bf16x8 bfr[2];
#pragma unroll
        for (int nt = 0; nt < 2; ++nt)
            bfr[nt] = *(const bf16x8*)&Blat[((kt * 2 + nt) * 64 + lane) * 8];
        asm volatile("s_waitcnt lgkmcnt(0)" ::: "memory");  // frags in regs
        __builtin_amdgcn_sched_barrier(0);
        if (kt < 6) issue1(kt + 2, buf);                    // overwrite is now safe
#pragma unroll
        for (int mt = 0; mt < 4; ++mt)
#pragma unroll
            for (int nt = 0; nt < 2; ++nt)
                acc1[mt][nt] = __builtin_amdgcn_mfma_f32_16x16x32_bf16(
                    a[mt], bfr[nt], acc1[mt][nt], 0, 0, 0);
    }

    // ---- issue stage-2 first two tiles; they land during the barrier drain ----
    issue2(0, 0);
    issue2(1, 1);

    // ---- U -> LDS (stage-2 fragment-linear, transposed) ----
#pragma unroll
    for (int mt = 0; mt < 4; ++mt) {
        int w0  = wave * 64 + mt * 16 + lkg * 4;
        int kt2 = w0 >> 5;
        int kg2 = (w0 >> 3) & 3;
        int j0  = w0 & 7;
#pragma unroll
        for (int nt = 0; nt < 2; ++nt) {
            f32x4 c = acc1[mt][nt];
            bf16x4 v4;
            v4[0] = (__bf16)c[0]; v4[1] = (__bf16)c[1];
            v4[2] = (__bf16)c[2]; v4[3] = (__bf16)c[3];
            *(bf16x4*)&Ut[((kt2 * 2 + nt) * 64 + kg2 * 16 + lrow) * 8 + j0] = v4;
        }
    }
    __syncthreads();   // also drains vmcnt -> stage-2 tiles 0,1 have landed

    // ---- stage 2 ----
    f32x4 acc2[MT][2] = {};
#pragma unroll
    for (int kt = 0; kt < 8; ++kt) {
        if (kt == 7) asm volatile("s_waitcnt vmcnt(0)" ::: "memory");
        else if constexpr (MT == 4) asm volatile("s_waitcnt vmcnt(4)" ::: "memory");
        else                        asm volatile("s_waitcnt vmcnt(2)" ::: "memory");
        const int buf = kt & 1;
        bf16x8 a[MT];
#pragma unroll
        for (int mt = 0; mt < MT; ++mt)
            a[mt] = *(const bf16x8*)&Astage[((wave * 2 + buf) * 4 + mt) * 512 + lane * 8];
        bf16x8 bfr[2];
#pragma unroll
        for (int nt = 0; nt < 2; ++nt)
            bfr[nt] = *(const bf16x8*)&Ut[((kt * 2 + nt) * 64 + lane) * 8];
        asm volatile("s_waitcnt lgkmcnt(0)" ::: "memory");
        __builtin_amdgcn_sched_barrier(0);
        if (kt < 6) issue2(kt + 2, buf);
#pragma unroll
        for (int mt = 0; mt < MT; ++mt)
#pragma unroll
            for (int nt = 0; nt < 2; ++nt)
                acc2[mt][nt] = __builtin_amdgcn_mfma_f32_16x16x32_bf16(
                    a[mt], bfr[nt], acc2[mt][nt], 0, 0, 0);
    }

    // ---- epilogue ----
    float* outc = out + ((size_t)b * CP + ch) * (size_t)(X_ * Y_);
#pragma unroll
    for (int mt = 0; mt < MT; ++mt) {
        int xb = xq * XCH + wave * (XCH / 4) + mt * 16 + lkg * 4;
#pragma unroll
        for (int nt = 0; nt < 2; ++nt) {
            int y = y0 + nt * 16 + lrow;
            f32x4 c = acc2[mt][nt];
            if (DENS) {
                *(f32x4*)&eeT0[((size_t)b * Y_ + y) * X_ + xb] = c;
#pragma unroll
                for (int r = 0; r < 4; ++r)
                    outc[(size_t)(xb + r) * Y_ + y] = c[r];
            } else {
                f32x4 e = *(const f32x4*)&eeT0[((size_t)b * Y_ + y) * X_ + xb];
#pragma unroll
                for (int r = 0; r < 4; ++r) {
                    float dcl = fminf(fmaxf(e[r], 1e-6f), 1e5f);
                    outc[(size_t)(xb + r) * Y_ + y] = c[r] / dcl;
                }
            }
        }
    }
}

extern "C" void kernel_launch(void* const* d_in, const int* in_sizes, int n_in,
                              void* d_out, int out_size, void* d_ws, size_t ws_size,
                              hipStream_t stream)
{
    const float* xin_lon  = (const float*)d_in[0];
    const float* xin_lat  = (const float*)d_in[1];
    const float* wt       = (const float*)d_in[2];
    const float* xout_lon = (const float*)d_in[3];
    const float* xout_lat = (const float*)d_in[4];
    const float* init_ls  = (const float*)d_in[5];
    float* out = (float*)d_out;

    __bf16* wlonT = (__bf16*)d_ws;
    __bf16* wlatT = wlonT + (size_t)B_ * X_ * W_;
    __bf16* wt33  = wlatT + (size_t)B_ * Y_ * H_;
    float*  eeT0  = (float*)(wt33 + (size_t)B_ * CP * W_ * H_);

    prep_kernel<<<6272, 256, 0, stream>>>(xin_lon, xin_lat, xout_lon, xout_lat,
                                          init_ls, wt, wlonT, wlatT, wt33);
    conv_mfma<4, true ><<<B_ * 16 * 4, 256, 0, stream>>>(wt33, wlonT, wlatT, eeT0, out);
    conv_mfma<2, false><<<2048,        256, 0, stream>>>(wt33, wlonT, wlatT, eeT0, out);
}

// Round 7
// 70.311 us; speedup vs baseline: 1.3229x; 1.3229x over previous
//
#include <hip/hip_runtime.h>
#include <cstddef>

#define B_ 2
#define C_ 32
#define CP 33
#define W_ 256
#define H_ 256
#define X_ 512
#define Y_ 512

typedef __bf16 bf16x8 __attribute__((ext_vector_type(8)));
typedef __bf16 bf16x4 __attribute__((ext_vector_type(4)));
typedef float  f32x4  __attribute__((ext_vector_type(4)));

#define AS1 __attribute__((address_space(1)))
#define AS3 __attribute__((address_space(3)))

__device__ __forceinline__ void gload16_lds(const void* g, void* l) {
    // async global->LDS, 16B/lane, LDS dest = wave-uniform base + lane*16
    __builtin_amdgcn_global_load_lds((const AS1 void*)g, (AS3 void*)l, 16, 0, 0);
}

// ws layout (bf16 units unless noted):
//   wlonT [B][X][W]  262144        (row-major, K=W contiguous)
//   wlatT [B][Y][H]  262144        (row-major, K=H contiguous)
//   wt33  [B][CP][W][H]  4325376   (ch0=density, ch c=nan_to_num(wt[c-1]))
//   U_T   [B][CP][Y][W]  4325376   (stage-1 result, transposed, K=W contig)
//   eeT0  f32 [B][Y][X]  524288 f32
// total ~19.5 MB

// ---------------- prep: bf16 tables ----------------
__global__ __launch_bounds__(256) void prep_kernel(
    const float* __restrict__ xin_lon, const float* __restrict__ xin_lat,
    const float* __restrict__ xout_lon, const float* __restrict__ xout_lat,
    const float* __restrict__ init_ls, const float* __restrict__ wt,
    __bf16* __restrict__ wlonT, __bf16* __restrict__ wlatT,
    __bf16* __restrict__ wt33)
{
    const int NLON = B_ * X_ * W_;
    const int NLAT = B_ * Y_ * H_;
    int t = blockIdx.x * 256 + threadIdx.x;
    float ls = init_ls[0];
    float cc = -0.5f / (ls * ls);
    if (t < NLON) {
        int b = t / (X_ * W_);
        int r = t - b * (X_ * W_);
        int x = r >> 8;
        int w = r & (W_ - 1);
        float d = xin_lon[b * W_ + w] - xout_lon[b * X_ + x];
        wlonT[t] = (__bf16)__expf(cc * d * d);
    } else if (t < NLON + NLAT) {
        int j = t - NLON;
        int b = j / (Y_ * H_);
        int r = j - b * (Y_ * H_);
        int y = r >> 8;
        int h = r & (H_ - 1);
        float d = xin_lat[b * H_ + h] - xout_lat[b * Y_ + y];
        wlatT[j] = (__bf16)__expf(cc * d * d);
    } else {
        int j = t - (NLON + NLAT);
        int o = j * 4;
        int b = o / (CP * W_ * H_);
        int r = o - b * (CP * W_ * H_);
        int co = r / (W_ * H_);
        int p = r & (W_ * H_ - 1);
        float4 v;
        bf16x4 ov;
        if (co == 0) {
            v = *(const float4*)&wt[((size_t)b * C_) * (W_ * H_) + p];
            ov[0] = (__bf16)((v.x != v.x) ? 0.f : 1.f);
            ov[1] = (__bf16)((v.y != v.y) ? 0.f : 1.f);
            ov[2] = (__bf16)((v.z != v.z) ? 0.f : 1.f);
            ov[3] = (__bf16)((v.w != v.w) ? 0.f : 1.f);
        } else {
            v = *(const float4*)&wt[((size_t)b * C_ + (co - 1)) * (W_ * H_) + p];
            ov[0] = (__bf16)((v.x != v.x) ? 0.f : v.x);
            ov[1] = (__bf16)((v.y != v.y) ? 0.f : v.y);
            ov[2] = (__bf16)((v.z != v.z) ? 0.f : v.z);
            ov[3] = (__bf16)((v.w != v.w) ? 0.f : v.w);
        }
        *(bf16x4*)&wt33[o] = ov;
    }
}

// ---------------- batched 128x128xK256 MFMA GEMM tile ----------------
// C[m][n] = sum_k A[m][k] * B[n][k]; both operands row-major with row
// stride 256 (= K). Both staged per-BK=32-step via global_load_lds in
// FRAGMENT-LINEAR order (per-lane permuted global src, linear LDS dest,
// linear conflict-free ds_read_b128). Double-buffered, counted vmcnt(4),
// raw s_barrier (no drain). 4 waves (2m x 2n), each 64x64 = 4x4 frags.
// MODE 0: A=wt33 panel,  B=wlatT,  out = U_T (bf16, transposed)
// MODE 1: A=wlonT,       B=U_T ch0, out = out ch0 raw + eeT0
// MODE 2: A=wlonT,       B=U_T ch,  out = out ch (divided by clip(eeT0))
template<int MODE>
__global__ __launch_bounds__(256, 2) void gemm_tile(
    const __bf16* __restrict__ wt33, const __bf16* __restrict__ wlonT,
    const __bf16* __restrict__ wlatT, __bf16* __restrict__ U_T,
    float* __restrict__ eeT0, float* __restrict__ out)
{
    constexpr int K_ = 256;
    __shared__ __bf16 Atile[2][4096];   // 8 KB per buf
    __shared__ __bf16 Btile[2][4096];

    const int t    = threadIdx.x;
    const int lane = t & 63;
    const int wave = t >> 6;
    const int wm   = wave >> 1, wn = wave & 1;
    const int lrow = lane & 15, lkg = lane >> 4;

    const int bid = blockIdx.x;
    int bb, chh, mtile, ntile;
    const __bf16 *Abase, *Bbase;
    if constexpr (MODE == 0) {
        int p = bid >> 3, tile = bid & 7;
        mtile = tile >> 2; ntile = tile & 3;       // 2 x 4 tiles (W x Y)
        bb = (p >= CP) ? 1 : 0; chh = p - bb * CP;
        Abase = wt33 + (size_t)p * (W_ * H_) + (size_t)mtile * 128 * H_;
        Bbase = wlatT + (size_t)bb * (Y_ * H_) + (size_t)ntile * 128 * H_;
    } else if constexpr (MODE == 1) {
        bb = bid >> 4; int tile = bid & 15;
        mtile = tile >> 2; ntile = tile & 3;       // 4 x 4 tiles (X x Y)
        chh = 0;
        Abase = wlonT + (size_t)bb * (X_ * W_) + (size_t)mtile * 128 * W_;
        Bbase = U_T + (size_t)(bb * CP) * (Y_ * W_) + (size_t)ntile * 128 * W_;
    } else {
        int xcd = bid & 7, k = bid >> 3;           // 8 channels per XCD
        int g = k >> 4, tile = k & 15;
        mtile = tile >> 2; ntile = tile & 3;
        int bc = xcd * 8 + g;
        bb = bc >> 5; chh = (bc & 31) + 1;
        Abase = wlonT + (size_t)bb * (X_ * W_) + (size_t)mtile * 128 * W_;
        Bbase = U_T + (size_t)(bb * CP + chh) * (Y_ * W_) + (size_t)ntile * 128 * W_;
    }

    // staging decode: chunk c = i*256 + t covers a 128x32 tile in
    // fragment-linear order: row = (c>>8)*64 + ((c>>6)&3)*16 + (c&15),
    // k-subgroup = (c>>4)&3. Reads back as frag[grp] at [grp*64+lane]*8.
    int rowoff[2], ldsoff[2];
#pragma unroll
    for (int i = 0; i < 2; ++i) {
        int c = i * 256 + t;
        int row  = ((c >> 8) << 6) + (((c >> 6) & 3) << 4) + (c & 15);
        int col8 = (c >> 4) & 3;
        rowoff[i] = row * K_ + col8 * 8;
        ldsoff[i] = (i * 256 + wave * 64) * 8;     // wave-uniform LDS base
    }

    auto stage = [&](int buf, int kt) {
#pragma unroll
        for (int i = 0; i < 2; ++i) {
            gload16_lds((const void*)(Abase + rowoff[i] + kt * 32),
                        (void*)&Atile[buf][ldsoff[i]]);
            gload16_lds((const void*)(Bbase + rowoff[i] + kt * 32),
                        (void*)&Btile[buf][ldsoff[i]]);
        }
    };

    f32x4 acc[4][4] = {};
    stage(0, 0);
#pragma unroll
    for (int kt = 0; kt < 8; ++kt) {
        const int buf = kt & 1;
        if (kt < 7) {
            stage(buf ^ 1, kt + 1);
            asm volatile("s_waitcnt vmcnt(4)" ::: "memory");  // cur tile landed
        } else {
            asm volatile("s_waitcnt vmcnt(0)" ::: "memory");
        }
        __builtin_amdgcn_s_barrier();
        bf16x8 af[4], bf[4];
#pragma unroll
        for (int mt = 0; mt < 4; ++mt)
            af[mt] = *(const bf16x8*)&Atile[buf][((wm * 4 + mt) * 64 + lane) * 8];
#pragma unroll
        for (int nt = 0; nt < 4; ++nt)
            bf[nt] = *(const bf16x8*)&Btile[buf][((wn * 4 + nt) * 64 + lane) * 8];
#pragma unroll
        for (int mt = 0; mt < 4; ++mt)
#pragma unroll
            for (int nt = 0; nt < 4; ++nt)
                acc[mt][nt] = __builtin_amdgcn_mfma_f32_16x16x32_bf16(
                    af[mt], bf[nt], acc[mt][nt], 0, 0, 0);
        __builtin_amdgcn_sched_barrier(0);   // pin reads+MFMAs before barrier
        __builtin_amdgcn_s_barrier();        // buf safe to overwrite next iter
    }

    // ---- epilogue ----
#pragma unroll
    for (int mt = 0; mt < 4; ++mt) {
#pragma unroll
        for (int nt = 0; nt < 4; ++nt) {
            int mg = mtile * 128 + wm * 64 + mt * 16 + lkg * 4;  // w (M0) / x
            int ng = ntile * 128 + wn * 64 + nt * 16 + lrow;     // y
            f32x4 c = acc[mt][nt];
            if constexpr (MODE == 0) {
                bf16x4 v4;
                v4[0] = (__bf16)c[0]; v4[1] = (__bf16)c[1];
                v4[2] = (__bf16)c[2]; v4[3] = (__bf16)c[3];
                __bf16* up = U_T + (size_t)(bb * CP + chh) * (Y_ * W_);
                *(bf16x4*)&up[(size_t)ng * W_ + mg] = v4;
            } else if constexpr (MODE == 1) {
                *(f32x4*)&eeT0[((size_t)bb * Y_ + ng) * X_ + mg] = c;
                float* outc = out + (size_t)bb * CP * (X_ * Y_);
#pragma unroll
                for (int r = 0; r < 4; ++r)
                    outc[(size_t)(mg + r) * Y_ + ng] = c[r];
            } else {
                f32x4 e = *(const f32x4*)&eeT0[((size_t)bb * Y_ + ng) * X_ + mg];
                float* outc = out + ((size_t)bb * CP + chh) * (X_ * Y_);
#pragma unroll
                for (int r = 0; r < 4; ++r) {
                    float dcl = fminf(fmaxf(e[r], 1e-6f), 1e5f);
                    outc[(size_t)(mg + r) * Y_ + ng] = c[r] / dcl;
                }
            }
        }
    }
}

extern "C" void kernel_launch(void* const* d_in, const int* in_sizes, int n_in,
                              void* d_out, int out_size, void* d_ws, size_t ws_size,
                              hipStream_t stream)
{
    const float* xin_lon  = (const float*)d_in[0];
    const float* xin_lat  = (const float*)d_in[1];
    const float* wt       = (const float*)d_in[2];
    const float* xout_lon = (const float*)d_in[3];
    const float* xout_lat = (const float*)d_in[4];
    const float* init_ls  = (const float*)d_in[5];
    float* out = (float*)d_out;

    __bf16* wlonT = (__bf16*)d_ws;
    __bf16* wlatT = wlonT + (size_t)B_ * X_ * W_;
    __bf16* wt33  = wlatT + (size_t)B_ * Y_ * H_;
    __bf16* U_T   = wt33 + (size_t)B_ * CP * W_ * H_;
    float*  eeT0  = (float*)(U_T + (size_t)B_ * CP * Y_ * W_);

    prep_kernel<<<6272, 256, 0, stream>>>(xin_lon, xin_lat, xout_lon, xout_lat,
                                          init_ls, wt, wlonT, wlatT, wt33);
    gemm_tile<0><<<B_ * CP * 8, 256, 0, stream>>>(wt33, wlonT, wlatT, U_T, eeT0, out);
    gemm_tile<1><<<B_ * 16,     256, 0, stream>>>(wt33, wlonT, wlatT, U_T, eeT0, out);
    gemm_tile<2><<<1024,        256, 0, stream>>>(wt33, wlonT, wlatT, U_T, eeT0, out);
}